// Round 11
// baseline (781.235 us; speedup 1.0000x reference)
//
#include <hip/hip_runtime.h>
#include <hip/hip_bf16.h>

typedef __attribute__((ext_vector_type(4)))  float  f32x4;
typedef __attribute__((ext_vector_type(16))) float  f32x16;
typedef __attribute__((ext_vector_type(8)))  short  bf16x8;
typedef __attribute__((ext_vector_type(4)))  int    i32x4;

#define M_DIM 8192
#define N_DIM 11008
#define K_DIM 4096
#define KP    2048

#define A_WS_BYTES ((size_t)M_DIM * K_DIM * 2)
#define B_WS_BYTES ((size_t)N_DIM * K_DIM * 2)
#define WS_NEED    (A_WS_BYTES + B_WS_BYTES)

// ---- 256x256 tile, BK=64, 8 waves (2Mx4N), 2 LDS buffers, 8-phase schedule ----
// MFMA shape: 32x32x16 (wave tile 128x64 = 4 m-blocks x 2 n-blocks of 32)
#define BM 256
#define BN 256
#define BK 64
#define NT  (K_DIM / BK)     // 64 K-tiles
#define NIT (NT / 2)         // 32 iterations (2 tiles/iter)
#define HALF_BYTES 16384     // 128 rows x 64 cols x 2B
#define ABUF_BYTES 32768     // A region per buffer (2 halves)
#define BUF_BYTES  65536     // A + B per buffer
// LDS total: 2 * 65536 = 131072

__device__ __forceinline__ short f2bf(float f) {
    return __builtin_bit_cast(short, __float2bfloat16(f));
}

// ---------------- prepass: x fp32 -> bf16 ----------------
__global__ __launch_bounds__(256)
void cvt_x_kernel(const float* __restrict__ x, short* __restrict__ xb)
{
    const size_t i = ((size_t)blockIdx.x * 256 + threadIdx.x) * 8;
    const f32x4 a = *(const f32x4*)(x + i);
    const f32x4 b = *(const f32x4*)(x + i + 4);
    bf16x8 o;
    #pragma unroll
    for (int j = 0; j < 4; ++j) {
        o[j]     = f2bf(a[j]);
        o[4 + j] = f2bf(b[j]);
    }
    *(bf16x8*)(xb + i) = o;
}

// ---------------- prepass: packed int4 -> bf16 ----------------
__global__ __launch_bounds__(256)
void dequant_w_kernel(const int* __restrict__ wq, short* __restrict__ wb)
{
    const size_t i = ((size_t)blockIdx.x * 256 + threadIdx.x) * 4;
    const i32x4 v = *(const i32x4*)(wq + i);
    bf16x8 o;
    #pragma unroll
    for (int j = 0; j < 4; ++j) {
        const int q = (v[j] & 0xFF) ^ 0x88;
        o[2 * j]     = f2bf((float)((q & 15) - 8));
        o[2 * j + 1] = f2bf((float)(((q >> 4) & 15) - 8));
    }
    *(bf16x8*)(wb + i * 2) = o;
}

// ---------------- main GEMM: 8-phase template (R5 schedule) + 32x32x16 MFMA ----------------
__global__ __launch_bounds__(512, 2)
void gemm256_kernel(const short* __restrict__ A,     // [8192][4096] bf16
                    const short* __restrict__ Bw,    // [11008][4096] bf16
                    const float* __restrict__ scale,
                    const float* __restrict__ bias,
                    float* __restrict__ out)
{
    __shared__ char lds[2 * BUF_BYTES];   // 128 KiB

    const int t    = threadIdx.x;
    const int lane = t & 63;
    const int wv   = t >> 6;          // 0..7
    const int wm   = wv >> 2;         // 0..1 -> M half (128 rows)
    const int wn   = wv & 3;          // 0..3 -> N quarter (64 cols)

    // bijective XCD chunk swizzle (nwg = 1376, %8 == 0)
    const int nbx = N_DIM / BN;                       // 43
    const int cpx = (nbx * (M_DIM / BM)) >> 3;        // 172
    const int bid = blockIdx.x;
    const int sid = (bid & 7) * cpx + (bid >> 3);
    const int by  = sid / nbx;
    const int bx  = sid - by * nbx;
    const int m0  = by * BM;
    const int n0  = bx * BN;

    // ---- staging geometry: identical to R5/R10 (verified) ----
    const int srow = t >> 3;                               // 0..63
    const int scol = ((t & 7) ^ (srow & 7)) * 8;           // element offset in row
    const short* aS = A  + (size_t)(m0 + srow) * K_DIM + scol;
    const short* bS = Bw + (size_t)(n0 + srow) * K_DIM + scol;

#define STG(SRC, MOFF, BUFI, H, KOFF) do {                                                  \
    _Pragma("unroll")                                                                       \
    for (int i_ = 0; i_ < 2; ++i_)                                                          \
        __builtin_amdgcn_global_load_lds(                                                   \
            (const __attribute__((address_space(1))) unsigned int*)                         \
                ((SRC) + ((H) * 128 + i_ * 64) * (size_t)K_DIM + (KOFF)),                   \
            (__attribute__((address_space(3))) unsigned int*)                               \
                (lds + (BUFI) * BUF_BYTES + (MOFF) + (H) * HALF_BYTES + i_ * 8192 + t * 16),\
            16, 0, 0);                                                                      \
} while (0)

    // ---- fragment read offsets for 32x32x16 ----
    // A-frag (mb, kk): row = wm*128 + mb*32 + (lane&31); 16B at granule ((kk<<1)|hi)^(row&7)
    //   = (kk<<1) ^ hi ^ (row&7)  ->  addr = aOff[mb] ^ (kk<<5)
    const int l31 = lane & 31;
    const int hi  = lane >> 5;        // k-group within k16
    int aOff[4], bOff[2];
    #pragma unroll
    for (int mb = 0; mb < 4; ++mb) {
        const int row = wm * 128 + mb * 32 + l31;
        aOff[mb] = row * 128 + (((hi ^ (row & 7)) & 7) << 4);
    }
    #pragma unroll
    for (int nb = 0; nb < 2; ++nb) {
        const int row = wn * 64 + nb * 32 + l31;
        bOff[nb] = ABUF_BYTES + row * 128 + (((hi ^ (row & 7)) & 7) << 4);
    }

    f32x16 acc[4][2];
    #pragma unroll
    for (int mb = 0; mb < 4; ++mb)
        #pragma unroll
        for (int nb = 0; nb < 2; ++nb)
            acc[mb][nb] = (f32x16)(0.f);

    bf16x8 af[2][4], bf[2][4];   // af: 2 live m-blocks x 4 k16; bf: 2 n-blocks x 4 k16

#define RDA(BUFP, MBASE) do {                                                    \
    _Pragma("unroll")                                                            \
    for (int m_ = 0; m_ < 2; ++m_)                                               \
        _Pragma("unroll")                                                        \
        for (int kk_ = 0; kk_ < 4; ++kk_)                                        \
            af[m_][kk_] = *(const bf16x8*)((BUFP) + (aOff[(MBASE) + m_] ^ (kk_ << 5))); \
} while (0)

#define RDB(BUFP, NB) do {                                                       \
    _Pragma("unroll")                                                            \
    for (int kk_ = 0; kk_ < 4; ++kk_)                                            \
        bf[NB][kk_] = *(const bf16x8*)((BUFP) + (bOff[NB] ^ (kk_ << 5)));        \
} while (0)

#define MFMAQ(MBASE, NB) do {                                                    \
    __builtin_amdgcn_s_setprio(1);                                               \
    _Pragma("unroll")                                                            \
    for (int m_ = 0; m_ < 2; ++m_)                                               \
        _Pragma("unroll")                                                        \
        for (int kk_ = 0; kk_ < 4; ++kk_)                                        \
            acc[(MBASE) + m_][NB] = __builtin_amdgcn_mfma_f32_32x32x16_bf16(     \
                af[m_][kk_], bf[NB][kk_], acc[(MBASE) + m_][NB], 0, 0, 0);       \
    __builtin_amdgcn_s_setprio(0);                                               \
} while (0)

#define BAR   __builtin_amdgcn_s_barrier()
#define LGKM0 asm volatile("s_waitcnt lgkmcnt(0)" ::: "memory")
#define VMC(N) asm volatile("s_waitcnt vmcnt(" #N ")" ::: "memory")

    // ---- prologue: identical stage slots to R5/R10 ----
    STG(bS, ABUF_BYTES, 0, 0, 0);
    STG(bS, ABUF_BYTES, 0, 1, 0);
    STG(aS, 0,          0, 0, 0);
    STG(aS, 0,          0, 1, 0);
    STG(bS, ABUF_BYTES, 1, 0, BK);
    STG(bS, ABUF_BYTES, 1, 1, BK);
    VMC(4);                       // drain tile0 (8 oldest loads); tile1-B may fly
    BAR;

    const char* b0p = lds;
    const char* b1p = lds + BUF_BYTES;

    for (int it = 0; it < NIT; ++it) {
        const int kc1 = (2 * it + 1) * BK;
        const int kn0 = (2 * it + 2) * BK;
        const int kn1 = (2 * it + 3) * BK;
        const bool nl = (it + 1 < NIT);

        // ---- P1: (mb0-1, nb0) of tile 2i (buf0) ----
        RDA(b0p, 0); RDB(b0p, 0);
        STG(aS, 0, 1, 0, kc1);
        BAR; LGKM0; MFMAQ(0, 0); BAR;
        // ---- P2: (mb0-1, nb1) ----
        RDB(b0p, 1);
        STG(aS, 0, 1, 1, kc1);
        BAR; LGKM0; MFMAQ(0, 1); BAR;
        // ---- P3: (mb2-3, nb1) ----
        RDA(b0p, 2);
        if (nl) STG(bS, ABUF_BYTES, 0, 0, kn0);
        BAR; LGKM0; MFMAQ(2, 1); BAR;
        // ---- P4: (mb2-3, nb0) — no reads; bf[0], af live ----
        if (nl) STG(bS, ABUF_BYTES, 0, 1, kn0);
        BAR; MFMAQ(2, 0);
        if (nl) VMC(4); else VMC(0);
        BAR;

        // ---- P5: (mb0-1, nb0) of tile 2i+1 (buf1) ----
        RDA(b1p, 0); RDB(b1p, 0);
        if (nl) STG(aS, 0, 0, 0, kn0);
        BAR; LGKM0; MFMAQ(0, 0); BAR;
        // ---- P6: (mb0-1, nb1) ----
        RDB(b1p, 1);
        if (nl) STG(aS, 0, 0, 1, kn0);
        BAR; LGKM0; MFMAQ(0, 1); BAR;
        // ---- P7: (mb2-3, nb1) ----
        RDA(b1p, 2);
        if (nl) STG(bS, ABUF_BYTES, 1, 0, kn1);
        BAR; LGKM0; MFMAQ(2, 1); BAR;
        // ---- P8: (mb2-3, nb0) ----
        if (nl) STG(bS, ABUF_BYTES, 1, 1, kn1);
        BAR; MFMAQ(2, 0);
        VMC(4);
        if (nl) BAR;
    }

    // ---- epilogue: out = acc * scale[n] + bias[n] ----
    // 32x32 C/D layout (verified m74/m101): col = lane&31, row = (reg&3) + 8*(reg>>2) + 4*(lane>>5)
    #pragma unroll
    for (int nb = 0; nb < 2; ++nb) {
        const int gn = n0 + wn * 64 + nb * 32 + l31;
        const float sc = scale[gn];
        const float bi = bias[gn];
        #pragma unroll
        for (int mb = 0; mb < 4; ++mb) {
            const int rbase = m0 + wm * 128 + mb * 32 + 4 * hi;
            const f32x16 v = acc[mb][nb];
            #pragma unroll
            for (int rg = 0; rg < 16; ++rg) {
                const int row = rbase + (rg & 3) + 8 * (rg >> 2);
                out[(size_t)row * N_DIM + gn] = v[rg] * sc + bi;
            }
        }
    }
#undef STG
#undef RDA
#undef RDB
#undef MFMAQ
#undef BAR
#undef LGKM0
#undef VMC
}

// ---------------- fallback: fused dequant GEMM (R1 kernel, known-good) ----------------
__device__ __forceinline__ int swz(int row, int kbyte) {
    return row * 128 + (kbyte ^ ((row & 7) << 4));
}

__global__ __launch_bounds__(256, 2)
void qlin_kernel(const float* __restrict__ x,
                 const int*   __restrict__ wq,
                 const float* __restrict__ scale,
                 const float* __restrict__ bias,
                 float* __restrict__ out)
{
    __shared__ short As[128 * 64];
    __shared__ short Bs[128 * 64];

    const int t  = threadIdx.x;
    const int n0 = blockIdx.x * 128;
    const int m0 = blockIdx.y * 128;

    const int sr = t >> 1;
    const int sh = t & 1;

    const float* ag = x  + (size_t)(m0 + sr) * K_DIM + sh * 32;
    const int*   bg = wq + (size_t)(n0 + sr) * KP    + sh * 16;

    const int lane = t & 63;
    const int wv   = t >> 6;
    const int wm   = wv >> 1;
    const int wn   = wv & 1;
    const int lr   = lane & 15;
    const int lk   = lane >> 4;

    f32x4 acc[4][4];
    #pragma unroll
    for (int i = 0; i < 4; ++i)
        #pragma unroll
        for (int j = 0; j < 4; ++j)
            acc[i][j] = (f32x4){0.f, 0.f, 0.f, 0.f};

    f32x4 ar[8];
    i32x4 br[4];

    #pragma unroll
    for (int i = 0; i < 8; ++i) ar[i] = *(const f32x4*)(ag + i * 4);
    #pragma unroll
    for (int i = 0; i < 4; ++i) br[i] = *(const i32x4*)(bg + i * 4);

    for (int kt = 0; kt < 64; ++kt) {
        #pragma unroll
        for (int c = 0; c < 4; ++c) {
            bf16x8 pa;
            #pragma unroll
            for (int j = 0; j < 8; ++j)
                pa[j] = f2bf(ar[c * 2 + (j >> 2)][j & 3]);
            *(bf16x8*)((char*)As + swz(sr, sh * 64 + c * 16)) = pa;

            bf16x8 pb;
            #pragma unroll
            for (int j = 0; j < 4; ++j) {
                const int q = br[c][j] ^ 0x88;
                const float flo = __builtin_bit_cast(float, 0x4B000000 | (q & 15))        - 8388616.0f;
                const float fhi = __builtin_bit_cast(float, 0x4B000000 | ((q >> 4) & 15)) - 8388616.0f;
                pb[2 * j]     = f2bf(flo);
                pb[2 * j + 1] = f2bf(fhi);
            }
            *(bf16x8*)((char*)Bs + swz(sr, sh * 64 + c * 16)) = pb;
        }
        __syncthreads();

        if (kt + 1 < 64) {
            const float* an = ag + (kt + 1) * 64;
            const int*   bn = bg + (kt + 1) * 32;
            #pragma unroll
            for (int i = 0; i < 8; ++i) ar[i] = *(const f32x4*)(an + i * 4);
            #pragma unroll
            for (int i = 0; i < 4; ++i) br[i] = *(const i32x4*)(bn + i * 4);
        }

        #pragma unroll
        for (int ks = 0; ks < 2; ++ks) {
            const int kb = ks * 64 + lk * 16;
            bf16x8 af2[4], bf2[4];
            #pragma unroll
            for (int mi = 0; mi < 4; ++mi)
                af2[mi] = *(const bf16x8*)((const char*)As + swz(wm * 64 + mi * 16 + lr, kb));
            #pragma unroll
            for (int ni = 0; ni < 4; ++ni)
                bf2[ni] = *(const bf16x8*)((const char*)Bs + swz(wn * 64 + ni * 16 + lr, kb));
            #pragma unroll
            for (int mi = 0; mi < 4; ++mi)
                #pragma unroll
                for (int ni = 0; ni < 4; ++ni)
                    acc[mi][ni] = __builtin_amdgcn_mfma_f32_16x16x32_bf16(
                        af2[mi], bf2[ni], acc[mi][ni], 0, 0, 0);
        }
        __syncthreads();
    }

    #pragma unroll
    for (int ni = 0; ni < 4; ++ni) {
        const int gn = n0 + wn * 64 + ni * 16 + lr;
        const float sc = scale[gn];
        const float bi = bias[gn];
        #pragma unroll
        for (int mi = 0; mi < 4; ++mi) {
            const int gm = m0 + wm * 64 + mi * 16 + lk * 4;
            const f32x4 v = acc[mi][ni];
            #pragma unroll
            for (int r2 = 0; r2 < 4; ++r2)
                out[(size_t)(gm + r2) * N_DIM + gn] = v[r2] * sc + bi;
        }
    }
}

extern "C" void kernel_launch(void* const* d_in, const int* in_sizes, int n_in,
                              void* d_out, int out_size, void* d_ws, size_t ws_size,
                              hipStream_t stream)
{
    const float* x     = (const float*)d_in[0];
    const int*   wq    = (const int*)d_in[1];
    const float* scale = (const float*)d_in[2];
    const float* bias  = (const float*)d_in[3];
    float*       out   = (float*)d_out;

    if (ws_size >= WS_NEED) {
        short* xb = (short*)d_ws;
        short* wb = (short*)((char*)d_ws + A_WS_BYTES);
        cvt_x_kernel<<<16384, 256, 0, stream>>>(x, xb);
        dequant_w_kernel<<<22016, 256, 0, stream>>>(wq, wb);
        const int nwg = (N_DIM / BN) * (M_DIM / BM);   // 43*32 = 1376
        gemm256_kernel<<<nwg, 512, 0, stream>>>(xb, wb, scale, bias, out);
    } else {
        qlin_kernel<<<dim3(N_DIM / 128, M_DIM / 128), 256, 0, stream>>>(x, wq, scale, bias, out);
    }
}

// Round 12
// 734.207 us; speedup vs baseline: 1.0641x; 1.0641x over previous
//
#include <hip/hip_runtime.h>
#include <hip/hip_bf16.h>

typedef __attribute__((ext_vector_type(4))) float  f32x4;
typedef __attribute__((ext_vector_type(8))) short  bf16x8;
typedef __attribute__((ext_vector_type(4))) int    i32x4;

#define M_DIM 8192
#define N_DIM 11008
#define K_DIM 4096
#define KP    2048

#define A_WS_BYTES ((size_t)M_DIM * K_DIM * 2)
#define B_WS_BYTES ((size_t)N_DIM * K_DIM * 2)
#define WS_NEED    (A_WS_BYTES + B_WS_BYTES)

// ---- 256x256 tile, BK=64, 8 waves (2Mx4N), 2 LDS buffers, 8-phase schedule ----
#define BM 256
#define BN 256
#define BK 64
#define NT  (K_DIM / BK)     // 64 K-tiles
#define NIT (NT / 2)         // 32 iterations (2 tiles/iter)
#define HALF_BYTES 16384     // 128 rows x 64 cols x 2B
#define ABUF_BYTES 32768     // A region per buffer (2 halves)
#define BUF_BYTES  65536     // A + B per buffer
// LDS total: 2 * 65536 = 131072

__device__ __forceinline__ short f2bf(float f) {
    return __builtin_bit_cast(short, __float2bfloat16(f));
}

// ---------------- prepass: x fp32 -> bf16 ----------------
__global__ __launch_bounds__(256)
void cvt_x_kernel(const float* __restrict__ x, short* __restrict__ xb)
{
    const size_t i = ((size_t)blockIdx.x * 256 + threadIdx.x) * 8;
    const f32x4 a = *(const f32x4*)(x + i);
    const f32x4 b = *(const f32x4*)(x + i + 4);
    bf16x8 o;
    #pragma unroll
    for (int j = 0; j < 4; ++j) {
        o[j]     = f2bf(a[j]);
        o[4 + j] = f2bf(b[j]);
    }
    *(bf16x8*)(xb + i) = o;
}

// ---------------- prepass: packed int4 -> bf16 ----------------
__global__ __launch_bounds__(256)
void dequant_w_kernel(const int* __restrict__ wq, short* __restrict__ wb)
{
    const size_t i = ((size_t)blockIdx.x * 256 + threadIdx.x) * 4;
    const i32x4 v = *(const i32x4*)(wq + i);
    bf16x8 o;
    #pragma unroll
    for (int j = 0; j < 4; ++j) {
        const int q = (v[j] & 0xFF) ^ 0x88;
        o[2 * j]     = f2bf((float)((q & 15) - 8));
        o[2 * j + 1] = f2bf((float)(((q >> 4) & 15) - 8));
    }
    *(bf16x8*)(wb + i * 2) = o;
}

// ---------------- main GEMM: 8-phase m201-template port (R5/R10, verified best) ----------------
__global__ __launch_bounds__(512, 2)
void gemm256_kernel(const short* __restrict__ A,     // [8192][4096] bf16
                    const short* __restrict__ Bw,    // [11008][4096] bf16
                    const float* __restrict__ scale,
                    const float* __restrict__ bias,
                    float* __restrict__ out)
{
    __shared__ char lds[2 * BUF_BYTES];   // 128 KiB

    const int t    = threadIdx.x;
    const int lane = t & 63;
    const int wv   = t >> 6;          // 0..7
    const int wm   = wv >> 2;         // 0..1 -> M half (128 rows)
    const int wn   = wv & 3;          // 0..3 -> N quarter (64 rows)

    // bijective XCD chunk swizzle (nwg = 1376, %8 == 0)
    const int nbx = N_DIM / BN;                       // 43
    const int cpx = (nbx * (M_DIM / BM)) >> 3;        // 172
    const int bid = blockIdx.x;
    const int sid = (bid & 7) * cpx + (bid >> 3);
    const int by  = sid / nbx;
    const int bx  = sid - by * nbx;
    const int m0  = by * BM;
    const int n0  = bx * BN;

    // ---- staging geometry: thread t covers row (t>>3)+{0,64}+h*128, granule t&7 ----
    // LDS phys (row, g) holds logical (row, g ^ (row&7)); source pre-swizzled (rule #21).
    const int srow = t >> 3;                               // 0..63
    const int scol = ((t & 7) ^ (srow & 7)) * 8;           // element offset in row
    const short* aS = A  + (size_t)(m0 + srow) * K_DIM + scol;
    const short* bS = Bw + (size_t)(n0 + srow) * K_DIM + scol;

#define STG(SRC, MOFF, BUFI, H, KOFF) do {                                                  \
    _Pragma("unroll")                                                                       \
    for (int i_ = 0; i_ < 2; ++i_)                                                          \
        __builtin_amdgcn_global_load_lds(                                                   \
            (const __attribute__((address_space(1))) unsigned int*)                         \
                ((SRC) + ((H) * 128 + i_ * 64) * (size_t)K_DIM + (KOFF)),                   \
            (__attribute__((address_space(3))) unsigned int*)                               \
                (lds + (BUFI) * BUF_BYTES + (MOFF) + (H) * HALF_BYTES + i_ * 8192 + t * 16),\
            16, 0, 0);                                                                      \
} while (0)

    // ---- fragment read offsets (within a buffer); ks1 = offset ^ 64 ----
    const int lr = lane & 15;
    const int lk = lane >> 4;
    int aOff[8], bOff[4];
    #pragma unroll
    for (int mi = 0; mi < 8; ++mi) {
        const int row = wm * 128 + mi * 16 + lr;
        aOff[mi] = row * 128 + ((lk ^ (row & 7)) * 16);
    }
    #pragma unroll
    for (int ni = 0; ni < 4; ++ni) {
        const int row = wn * 64 + ni * 16 + lr;
        bOff[ni] = ABUF_BYTES + row * 128 + ((lk ^ (row & 7)) * 16);
    }

    f32x4 acc[8][4];
    #pragma unroll
    for (int mi = 0; mi < 8; ++mi)
        #pragma unroll
        for (int ni = 0; ni < 4; ++ni)
            acc[mi][ni] = (f32x4){0.f, 0.f, 0.f, 0.f};

    bf16x8 af[4][2], bf[4][2];

#define RDA(BUFP, MIBASE) do {                                                   \
    _Pragma("unroll")                                                            \
    for (int m_ = 0; m_ < 4; ++m_) {                                             \
        af[m_][0] = *(const bf16x8*)((BUFP) + aOff[(MIBASE) + m_]);              \
        af[m_][1] = *(const bf16x8*)((BUFP) + (aOff[(MIBASE) + m_] ^ 64));       \
    }                                                                            \
} while (0)

#define RDB(BUFP, NIBASE) do {                                                   \
    _Pragma("unroll")                                                            \
    for (int n_ = 0; n_ < 2; ++n_) {                                             \
        bf[(NIBASE) + n_][0] = *(const bf16x8*)((BUFP) + bOff[(NIBASE) + n_]);   \
        bf[(NIBASE) + n_][1] = *(const bf16x8*)((BUFP) + (bOff[(NIBASE) + n_] ^ 64)); \
    }                                                                            \
} while (0)

#define MFMAQ(ACCMI, NIBASE) do {                                                \
    __builtin_amdgcn_s_setprio(1);                                               \
    _Pragma("unroll")                                                            \
    for (int m_ = 0; m_ < 4; ++m_)                                               \
        _Pragma("unroll")                                                        \
        for (int n_ = 0; n_ < 2; ++n_) {                                         \
            acc[(ACCMI) + m_][(NIBASE) + n_] = __builtin_amdgcn_mfma_f32_16x16x32_bf16( \
                af[m_][0], bf[(NIBASE) + n_][0], acc[(ACCMI) + m_][(NIBASE) + n_], 0, 0, 0); \
            acc[(ACCMI) + m_][(NIBASE) + n_] = __builtin_amdgcn_mfma_f32_16x16x32_bf16( \
                af[m_][1], bf[(NIBASE) + n_][1], acc[(ACCMI) + m_][(NIBASE) + n_], 0, 0, 0); \
        }                                                                        \
    __builtin_amdgcn_s_setprio(0);                                               \
} while (0)

#define BAR   __builtin_amdgcn_s_barrier()
#define LGKM0 asm volatile("s_waitcnt lgkmcnt(0)" ::: "memory")
#define VMC(N) asm volatile("s_waitcnt vmcnt(" #N ")" ::: "memory")

    // ---- prologue: emulate iter -1 stage slots ----
    // tile0 -> buf0 (B-h0, B-h1, A-h0, A-h1); tile1 B -> buf1 (B-h0, B-h1)
    STG(bS, ABUF_BYTES, 0, 0, 0);
    STG(bS, ABUF_BYTES, 0, 1, 0);
    STG(aS, 0,          0, 0, 0);
    STG(aS, 0,          0, 1, 0);
    STG(bS, ABUF_BYTES, 1, 0, BK);
    STG(bS, ABUF_BYTES, 1, 1, BK);
    VMC(4);                       // drain tile0 (8 oldest loads); tile1-B may fly
    BAR;

    const char* b0p = lds;
    const char* b1p = lds + BUF_BYTES;

    for (int it = 0; it < NIT; ++it) {
        const int kc1 = (2 * it + 1) * BK;   // buf1 tile (this iter)
        const int kn0 = (2 * it + 2) * BK;   // next buf0 tile
        const int kn1 = (2 * it + 3) * BK;   // next buf1 tile
        const bool nl = (it + 1 < NIT);

        // ---- P1: Q00 of tile 2i (buf0) ----
        RDA(b0p, 0); RDB(b0p, 0);
        STG(aS, 0, 1, 0, kc1);               // tile 2i+1 A-h0 (buf1-A freed prev P7)
        BAR; LGKM0; MFMAQ(0, 0); BAR;
        // ---- P2: Q01 ----
        RDB(b0p, 2);
        STG(aS, 0, 1, 1, kc1);               // tile 2i+1 A-h1
        BAR; LGKM0; MFMAQ(0, 2); BAR;
        // ---- P3: Q11 ----
        RDA(b0p, 4);
        if (nl) STG(bS, ABUF_BYTES, 0, 0, kn0);  // tile 2i+2 B-h0 (buf0-B freed after P2)
        BAR; LGKM0; MFMAQ(4, 2); BAR;
        // ---- P4: Q10 (no reads; bf[0-1], af[4-7] live) ----
        if (nl) STG(bS, ABUF_BYTES, 0, 1, kn0);  // tile 2i+2 B-h1
        BAR; MFMAQ(4, 0);
        if (nl) VMC(4); else VMC(0);         // drain tile 2i+1 A (P1,P2 stages)
        BAR;

        // ---- P5: Q00 of tile 2i+1 (buf1) ----
        RDA(b1p, 0); RDB(b1p, 0);
        if (nl) STG(aS, 0, 0, 0, kn0);       // tile 2i+2 A-h0 (buf0-A freed after P3)
        BAR; LGKM0; MFMAQ(0, 0); BAR;
        // ---- P6: Q01 ----
        RDB(b1p, 2);
        if (nl) STG(aS, 0, 0, 1, kn0);       // tile 2i+2 A-h1
        BAR; LGKM0; MFMAQ(0, 2); BAR;
        // ---- P7: Q11 ----
        RDA(b1p, 4);
        if (nl) STG(bS, ABUF_BYTES, 1, 0, kn1);  // tile 2i+3 B-h0 (buf1-B freed after P6)
        BAR; LGKM0; MFMAQ(4, 2); BAR;
        // ---- P8: Q10 ----
        if (nl) STG(bS, ABUF_BYTES, 1, 1, kn1);  // tile 2i+3 B-h1
        BAR; MFMAQ(4, 0);
        VMC(4);                               // drain tile 2i+2 (B at P3/P4, A at P5/P6)
        if (nl) BAR;
    }

    // ---- epilogue: out = acc * scale[n] + bias[n] ----
    // C/D layout: col = lane&15, row = (lane>>4)*4 + reg   (verified, passing R1-R11)
    #pragma unroll
    for (int ni = 0; ni < 4; ++ni) {
        const int gn = n0 + wn * 64 + ni * 16 + lr;
        const float sc = scale[gn];
        const float bi = bias[gn];
        #pragma unroll
        for (int mi = 0; mi < 8; ++mi) {
            const int gm = m0 + wm * 128 + mi * 16 + lk * 4;
            const f32x4 v = acc[mi][ni];
            #pragma unroll
            for (int r = 0; r < 4; ++r)
                out[(size_t)(gm + r) * N_DIM + gn] = v[r] * sc + bi;
        }
    }
#undef STG
#undef RDA
#undef RDB
#undef MFMAQ
#undef BAR
#undef LGKM0
#undef VMC
}

// ---------------- fallback: fused dequant GEMM (R1 kernel, known-good) ----------------
__device__ __forceinline__ int swz(int row, int kbyte) {
    return row * 128 + (kbyte ^ ((row & 7) << 4));
}

__global__ __launch_bounds__(256, 2)
void qlin_kernel(const float* __restrict__ x,
                 const int*   __restrict__ wq,
                 const float* __restrict__ scale,
                 const float* __restrict__ bias,
                 float* __restrict__ out)
{
    __shared__ short As[128 * 64];
    __shared__ short Bs[128 * 64];

    const int t  = threadIdx.x;
    const int n0 = blockIdx.x * 128;
    const int m0 = blockIdx.y * 128;

    const int sr = t >> 1;
    const int sh = t & 1;

    const float* ag = x  + (size_t)(m0 + sr) * K_DIM + sh * 32;
    const int*   bg = wq + (size_t)(n0 + sr) * KP    + sh * 16;

    const int lane = t & 63;
    const int wv   = t >> 6;
    const int wm   = wv >> 1;
    const int wn   = wv & 1;
    const int lr   = lane & 15;
    const int lk   = lane >> 4;

    f32x4 acc[4][4];
    #pragma unroll
    for (int i = 0; i < 4; ++i)
        #pragma unroll
        for (int j = 0; j < 4; ++j)
            acc[i][j] = (f32x4){0.f, 0.f, 0.f, 0.f};

    f32x4 ar[8];
    i32x4 br[4];

    #pragma unroll
    for (int i = 0; i < 8; ++i) ar[i] = *(const f32x4*)(ag + i * 4);
    #pragma unroll
    for (int i = 0; i < 4; ++i) br[i] = *(const i32x4*)(bg + i * 4);

    for (int kt = 0; kt < 64; ++kt) {
        #pragma unroll
        for (int c = 0; c < 4; ++c) {
            bf16x8 pa;
            #pragma unroll
            for (int j = 0; j < 8; ++j)
                pa[j] = f2bf(ar[c * 2 + (j >> 2)][j & 3]);
            *(bf16x8*)((char*)As + swz(sr, sh * 64 + c * 16)) = pa;

            bf16x8 pb;
            #pragma unroll
            for (int j = 0; j < 4; ++j) {
                const int q = br[c][j] ^ 0x88;
                const float flo = __builtin_bit_cast(float, 0x4B000000 | (q & 15))        - 8388616.0f;
                const float fhi = __builtin_bit_cast(float, 0x4B000000 | ((q >> 4) & 15)) - 8388616.0f;
                pb[2 * j]     = f2bf(flo);
                pb[2 * j + 1] = f2bf(fhi);
            }
            *(bf16x8*)((char*)Bs + swz(sr, sh * 64 + c * 16)) = pb;
        }
        __syncthreads();

        if (kt + 1 < 64) {
            const float* an = ag + (kt + 1) * 64;
            const int*   bn = bg + (kt + 1) * 32;
            #pragma unroll
            for (int i = 0; i < 8; ++i) ar[i] = *(const f32x4*)(an + i * 4);
            #pragma unroll
            for (int i = 0; i < 4; ++i) br[i] = *(const i32x4*)(bn + i * 4);
        }

        #pragma unroll
        for (int ks = 0; ks < 2; ++ks) {
            const int kb = ks * 64 + lk * 16;
            bf16x8 af2[4], bf2[4];
            #pragma unroll
            for (int mi = 0; mi < 4; ++mi)
                af2[mi] = *(const bf16x8*)((const char*)As + swz(wm * 64 + mi * 16 + lr, kb));
            #pragma unroll
            for (int ni = 0; ni < 4; ++ni)
                bf2[ni] = *(const bf16x8*)((const char*)Bs + swz(wn * 64 + ni * 16 + lr, kb));
            #pragma unroll
            for (int mi = 0; mi < 4; ++mi)
                #pragma unroll
                for (int ni = 0; ni < 4; ++ni)
                    acc[mi][ni] = __builtin_amdgcn_mfma_f32_16x16x32_bf16(
                        af2[mi], bf2[ni], acc[mi][ni], 0, 0, 0);
        }
        __syncthreads();
    }

    #pragma unroll
    for (int ni = 0; ni < 4; ++ni) {
        const int gn = n0 + wn * 64 + ni * 16 + lr;
        const float sc = scale[gn];
        const float bi = bias[gn];
        #pragma unroll
        for (int mi = 0; mi < 4; ++mi) {
            const int gm = m0 + wm * 64 + mi * 16 + lk * 4;
            const f32x4 v = acc[mi][ni];
            #pragma unroll
            for (int r2 = 0; r2 < 4; ++r2)
                out[(size_t)(gm + r2) * N_DIM + gn] = v[r2] * sc + bi;
        }
    }
}

extern "C" void kernel_launch(void* const* d_in, const int* in_sizes, int n_in,
                              void* d_out, int out_size, void* d_ws, size_t ws_size,
                              hipStream_t stream)
{
    const float* x     = (const float*)d_in[0];
    const int*   wq    = (const int*)d_in[1];
    const float* scale = (const float*)d_in[2];
    const float* bias  = (const float*)d_in[3];
    float*       out   = (float*)d_out;

    if (ws_size >= WS_NEED) {
        short* xb = (short*)d_ws;
        short* wb = (short*)((char*)d_ws + A_WS_BYTES);
        cvt_x_kernel<<<16384, 256, 0, stream>>>(x, xb);
        dequant_w_kernel<<<22016, 256, 0, stream>>>(wq, wb);
        const int nwg = (N_DIM / BN) * (M_DIM / BM);   // 43*32 = 1376
        gemm256_kernel<<<nwg, 512, 0, stream>>>(xb, wb, scale, bias, out);
    } else {
        qlin_kernel<<<dim3(N_DIM / 128, M_DIM / 128), 256, 0, stream>>>(x, wq, scale, bias, out);
    }
}